// Round 16
// baseline (423.088 us; speedup 1.0000x reference)
//
#include <hip/hip_runtime.h>

#define NDIS 5000
#define NGEN 20000
#define NTOT 25000
#define EDG  400000

typedef __attribute__((ext_vector_type(8))) short short8;
typedef __attribute__((ext_vector_type(4))) float f32x4;
typedef __attribute__((ext_vector_type(4), aligned(4))) float f32x4u;
typedef __attribute__((ext_vector_type(4))) unsigned int uint4v;
typedef __attribute__((ext_vector_type(2))) unsigned int uint2v;
typedef __attribute__((ext_vector_type(2), aligned(4))) unsigned int uint2a;

// ---------------- workspace layout ----------------
constexpr size_t AL(size_t x) { return (x + 255) & ~(size_t)255; }
constexpr size_t OFF_H0   = 0;
constexpr size_t OFF_PQ   = AL(OFF_H0  + (size_t)NTOT * 128 * 4);
constexpr size_t OFF_H1   = AL(OFF_PQ  + (size_t)NTOT * 128 * 4);
constexpr size_t OFF_DEG  = AL(OFF_H1  + (size_t)NTOT * 64 * 4);
constexpr size_t OFF_RS   = AL(OFF_DEG + (size_t)NTOT * 4);
constexpr size_t OFF_CUR  = AL(OFF_RS  + (size_t)(NTOT + 1) * 4);
constexpr size_t OFF_TMP  = AL(OFF_CUR + (size_t)NTOT * 4);
constexpr size_t OFF_BSUM = AL(OFF_TMP + (size_t)NTOT * 4);
constexpr size_t OFF_BOFF = AL(OFF_BSUM + 64 * 4);
constexpr size_t OFF_ESRC = AL(OFF_BOFF + 64 * 4);
constexpr size_t OFF_MIT  = AL(OFF_ESRC + (size_t)EDG * 4);
constexpr size_t OFF_BDIS = AL(OFF_MIT + (size_t)5000 * 2048 * 2);   // KT=76
constexpr size_t OFF_BGEN = AL(OFF_BDIS + (size_t)8 * 76 * 512 * 2); // KT=300
constexpr size_t OFF_BS1  = AL(OFF_BGEN + (size_t)8 * 300 * 512 * 2);
constexpr size_t OFF_BS2  = AL(OFF_BS1 + (size_t)8 * 4 * 512 * 2);
constexpr size_t OFF_PD   = AL(OFF_BS2 + (size_t)8 * 4 * 512 * 2);   // 5 x NDIS x 128 f32
constexpr size_t OFF_PG   = AL(OFF_PD + (size_t)5 * NDIS * 128 * 4); // 5 x NGEN x 128 f32

__device__ __forceinline__ ushort f2bf(float f) {
    unsigned u = __float_as_uint(f);
    u += 0x7fffu + ((u >> 16) & 1u);
    return (ushort)(u >> 16);
}

__device__ __forceinline__ unsigned cvtpk(float a, float b) {
    unsigned r;
    asm("v_cvt_pk_bf16_f32 %0, %1, %2" : "=v"(r) : "v"(a), "v"(b));
    return r;
}

__device__ __forceinline__ void MFMA(f32x4& d, short8 a, short8 b) {
    asm volatile("v_mfma_f32_16x16x32_bf16 %0, %1, %2, %0"
                 : "+v"(d) : "v"(a), "v"(b));
}

// ---------------- multi-descriptor transpose/convert/permute (+deg count) ----------------
struct TcvtIns { const float* p[9]; };

__global__ __launch_bounds__(256) void k_tcvt_multi(TcvtIns ins, char* ws,
                                                    const int* __restrict__ dst,
                                                    int* __restrict__ deg)
{
    constexpr int   TR[9]   = {383, 2000, 4395, 5000, 2000, 128, 128, 64, 64};
    constexpr int   TC[9]   = {128, 128, 128, 128, 5000, 64, 64, 64, 64};
    constexpr int   TKT[9]  = {76, 76, 300, 300, 2048 /*ld*/, 4, 4, 4, 4};
    constexpr int   TKO[9]  = {0, 12, 0, 140, 0, 0, 0, 0, 0};
    constexpr int   TRP[9]  = {384, 2048, 4480, 5120, 2048, 128, 128, 128, 128};
    constexpr int   TNOFF[9]= {0, 0, 0, 0, 0, 0, 64, 0, 64};
    constexpr int   TMODE[9]= {1, 1, 1, 1, 0, 1, 1, 1, 1};
    constexpr float TSC[9]  = {0.9f, 0.1f, 0.9f, 0.1f, 1.f, 1.f, 1.f, 1.f, 1.f};
    constexpr size_t TOUT[9]= {OFF_BDIS, OFF_BDIS, OFF_BGEN, OFF_BGEN, OFF_MIT,
                               OFF_BS1, OFF_BS1, OFF_BS2, OFF_BS2};
    constexpr int TNBX[9]   = {4, 4, 4, 4, 157, 2, 2, 2, 2};
    constexpr int PRE[10]   = {0, 48, 304, 864, 1504, 11552, 11560, 11568, 11576, 11584};

    int bid = blockIdx.x;
    if (bid >= 11584) {                       // fused degree count
        int e = (bid - 11584) * 256 + threadIdx.x;
        if (e < EDG) atomicAdd(&deg[dst[e]], 1);
        return;
    }
    int d = 0;
#pragma unroll
    for (int q = 1; q < 9; ++q) if (bid >= PRE[q]) d = q;
    int local = bid - PRE[d];
    int bx = local % TNBX[d], by = local / TNBX[d];
    const int R = TR[d], C = TC[d], KT = TKT[d], KO = TKO[d];
    const int Rp = TRP[d], noff = TNOFF[d];
    const float scale = TSC[d];
    const float* in = ins.p[d];
    ushort* out = (ushort*)(ws + TOUT[d]);

    __shared__ float t[32][33];
    int tx = threadIdx.x & 31, ty = threadIdx.x >> 5;
    int c0 = bx * 32, r0 = by * 32;
#pragma unroll
    for (int j = 0; j < 4; ++j) {
        int r = r0 + ty + j * 8, c = c0 + tx;
        t[ty + j * 8][tx] = (r < R && c < C) ? in[(size_t)r * C + c] : 0.f;
    }
    __syncthreads();
#pragma unroll
    for (int j = 0; j < 4; ++j) {
        int c = c0 + ty + j * 8, r = r0 + tx;
        if (c >= C || r >= Rp) continue;
        ushort bv = f2bf(scale * t[tx][ty + j * 8]);
        if (TMODE[d] == 0) {
            out[(size_t)c * KT + r] = bv;
        } else {
            int n = noff + c, k = r;
            out[(size_t)((n >> 4) * KT + KO + (k >> 5)) * 512 +
                ((k >> 3) & 3) * 128 + (n & 15) * 8 + (k & 7)] = bv;
        }
    }
}

// ---------------- streaming MFMA GEMM (merged 2-op dispatch) ----------------
// op: C[M,128] (+)= [A1 f32 (nst1 supertiles) | A2 (nst2, a2mode 1=f32 2=bf16)] @ Bf
// PARTIAL: per-split plain stores at C + gy*M*128. else direct + bias cols<64.
// Row-local clamp + per-element k-guards on boundary supertiles (R11 fix).
// launch_bounds(256,2): (256,4) spilled at R13.
struct EmbOp {
    const float* A1; int lda1, K1, nst1;
    const void* A2v; int lda2, K2, nst2;
    const ushort* Bf; int KT; float* C; int M; int a2mode;
};

template<bool PARTIAL>
__global__ __launch_bounds__(256, 2) void gemm_st(
    EmbOp opg, EmbOp opd, int bxsplit, const float* __restrict__ bias)
{
    const bool isg = (int)blockIdx.x < bxsplit;
    const EmbOp op = isg ? opg : opd;
    const float* __restrict__ A1 = op.A1;
    const int lda1 = op.lda1, K1 = op.K1, nst1 = op.nst1;
    const void* __restrict__ A2v = op.A2v;
    const int lda2 = op.lda2, K2 = op.K2, nst2 = op.nst2;
    const ushort* __restrict__ Bf = op.Bf;
    const int KT = op.KT, M = op.M, a2mode = op.a2mode;
    float* __restrict__ C = op.C;

    __shared__ ushort lds0[64 * 128];
    __shared__ ushort lds1[64 * 128];
    const int tid  = threadIdx.x;
    const int lane = tid & 63;
    const int w    = tid >> 6;
    const int fr = lane & 15, kq = lane >> 4;
    const int bm0 = (isg ? blockIdx.x : (blockIdx.x - bxsplit)) * 64;
    if (bm0 >= M + 63) return;

    const int NSTT = nst1 + nst2;
    const int per = (NSTT + gridDim.y - 1) / gridDim.y;
    const int s0 = blockIdx.y * per;
    const int s1 = min(NSTT, s0 + per);
    const int NT = s1 - s0;
    if (NT <= 0) return;

    f32x4 acc[4][2];
#pragma unroll
    for (int i = 0; i < 4; ++i) { acc[i][0] = {0.f,0.f,0.f,0.f}; acc[i][1] = {0.f,0.f,0.f,0.f}; }

    uint4v faA[8], faB[8];
    short8 Breg0[4][2], Breg1[4][2];

    const int srow = w * 16 + (lane >> 5);   // stage row base (this thread)
    const int scol = lane & 31;              // 4 k-values per thread

    auto issueA = [&](int stg, uint4v* fa) {
        const bool r1 = (a2mode == 0) || (stg < nst1);
#pragma unroll
        for (int i = 0; i < 8; ++i) {
            int r = bm0 + srow + i * 2;
            if (r > M - 1) r = M - 1;        // row-local clamp (value discarded in epilogue)
            if (r1) {
                const int kb = stg << 7;
                const int k = kb + scol * 4;
                const float* p = A1 + (size_t)r * lda1 + k;
                if (kb + 128 <= K1) {
                    fa[i] = __builtin_bit_cast(uint4v, *(const f32x4u*)p);
                } else {                      // boundary supertile: per-element guard
                    f32x4 v;
#pragma unroll
                    for (int e = 0; e < 4; ++e) v[e] = (k + e < K1) ? p[e] : 0.f;
                    fa[i] = __builtin_bit_cast(uint4v, v);
                }
            } else if (a2mode == 1) {
                const int kb = (stg - nst1) << 7;
                const int kc = kb + scol * 4;
                const float* p = (const float*)A2v + (size_t)r * lda2 + kc;
                if (kb + 128 <= K2) {
                    fa[i] = __builtin_bit_cast(uint4v, *(const f32x4u*)p);
                } else {
                    f32x4 v;
#pragma unroll
                    for (int e = 0; e < 4; ++e) v[e] = (kc + e < K2) ? p[e] : 0.f;
                    fa[i] = __builtin_bit_cast(uint4v, v);
                }
            } else {                          // bf16 A2: K2 multiple of 128, always full
                const int kc = ((stg - nst1) << 7) + scol * 4;
                uint2a v = *(const uint2a*)((const ushort*)A2v + (size_t)r * lda2 + kc);
                fa[i][0] = v[0]; fa[i][1] = v[1];
            }
        }
    };
    auto issueB = [&](int stg, short8 (*BR)[2]) {
#pragma unroll
        for (int ks = 0; ks < 4; ++ks)
#pragma unroll
            for (int nf = 0; nf < 2; ++nf)
                BR[ks][nf] = *(const short8*)(
                    Bf + (size_t)((w * 2 + nf) * KT + stg * 4 + ks) * 512 + lane * 8);
    };
    auto writeT = [&](int stg, const uint4v* fa, ushort* buf) {
        const bool cvt = (a2mode != 2) || (stg < nst1);
        const int G = scol >> 1, h = lane & 1;
#pragma unroll
        for (int i = 0; i < 8; ++i) {
            int r = srow + i * 2;
            const size_t off = (size_t)r * 256 + ((G ^ (r & 7)) << 4) + h * 8;
            uint2v d;
            if (cvt) {
                f32x4 v = __builtin_bit_cast(f32x4, fa[i]);
                d[0] = cvtpk(v[0], v[1]);
                d[1] = cvtpk(v[2], v[3]);
            } else {
                d[0] = fa[i][0]; d[1] = fa[i][1];
            }
            *(uint2v*)((char*)buf + off) = d;
        }
    };

#define PHASE(T, BR, LDSC, FAW, LDSW)                                        \
    {                                                                        \
        const int x7 = fr & 7;                                               \
        _Pragma("unroll")                                                    \
        for (int ks = 0; ks < 4; ++ks) {                                     \
            short8 af[4];                                                    \
            _Pragma("unroll")                                                \
            for (int mf = 0; mf < 4; ++mf)                                   \
                af[mf] = *(const short8*)&LDSC[fr * 128 + mf * 2048 +        \
                                              (((ks * 4 + kq) ^ x7) << 3)];  \
            _Pragma("unroll")                                                \
            for (int mf = 0; mf < 4; ++mf) {                                 \
                MFMA(acc[mf][0], af[mf], BR[ks][0]);                         \
                MFMA(acc[mf][1], af[mf], BR[ks][1]);                         \
            }                                                                \
        }                                                                    \
        if ((T) + 2 < NT) issueB(s0 + (T) + 2, BR);                          \
        __builtin_amdgcn_s_barrier();                                        \
        if ((T) + 1 < NT) {                                                  \
            writeT(s0 + (T) + 1, FAW, LDSW);                                 \
            if ((T) + 3 < NT) issueA(s0 + (T) + 3, FAW);                     \
            asm volatile("s_waitcnt lgkmcnt(0)" ::: "memory");               \
            __builtin_amdgcn_s_barrier();                                    \
        }                                                                    \
    }

    // prologue
    issueA(s0, faA); issueB(s0, Breg0);
    if (NT > 1) { issueA(s0 + 1, faB); issueB(s0 + 1, Breg1); }
    writeT(s0, faA, lds0);
    if (NT > 2) issueA(s0 + 2, faA);
    asm volatile("s_waitcnt lgkmcnt(0)" ::: "memory");
    __builtin_amdgcn_s_barrier();

    for (int t = 0; t < NT; t += 2) {
        PHASE(t, Breg0, lds0, faB, lds1);
        if (t + 1 < NT) PHASE(t + 1, Breg1, lds1, faA, lds0);
    }
#undef PHASE

    asm volatile("s_nop 7\n\ts_nop 7\n\ts_nop 7" ::: "memory");
    float* Cs = PARTIAL ? (C + (size_t)blockIdx.y * ((size_t)M * 128)) : C;
#pragma unroll
    for (int mf = 0; mf < 4; ++mf)
#pragma unroll
        for (int nf = 0; nf < 2; ++nf)
#pragma unroll
            for (int r = 0; r < 4; ++r) {
                int row = bm0 + mf * 16 + kq * 4 + r;
                if (row < M) {
                    int col = w * 32 + nf * 16 + fr;
                    if (PARTIAL) {
                        Cs[(size_t)row * 128 + col] = acc[mf][nf][r];
                    } else {
                        float v = acc[mf][nf][r];
                        if (col < 64) v += bias[col];
                        Cs[(size_t)row * 128 + col] = v;
                    }
                }
            }
}

// ---------------- reduce partials + scaled bias -> h0 ----------------
__global__ __launch_bounds__(256) void k_reduce(
    const float* __restrict__ Pd, const float* __restrict__ Pg,
    const float* __restrict__ bd, const float* __restrict__ bg,
    float* __restrict__ h0)
{
    int i = blockIdx.x * 256 + threadIdx.x;
    if (i >= NTOT * 128) return;
    int row = i >> 7, c = i & 127;
    float v;
    if (row < NDIS) {
        v = 0.9f * bd[c];
#pragma unroll
        for (int s = 0; s < 5; ++s) v += Pd[(size_t)s * NDIS * 128 + i];
    } else {
        v = 0.9f * bg[c];
        int j = i - NDIS * 128;
#pragma unroll
        for (int s = 0; s < 5; ++s) v += Pg[(size_t)s * NGEN * 128 + j];
    }
    h0[i] = v;
}

// ---------------- hierarchical CSR scan ----------------
__global__ __launch_bounds__(1024) void k_scan1(const int* __restrict__ deg,
                                                int* __restrict__ tmp,
                                                int* __restrict__ bsum, int n) {
    __shared__ int wsum[16];
    int t = threadIdx.x, lane = t & 63, wid = t >> 6;
    int i = blockIdx.x * 1024 + t;
    int v = (i < n) ? deg[i] : 0;
    int x = v;
#pragma unroll
    for (int off = 1; off < 64; off <<= 1) {
        int y = __shfl_up(x, off, 64);
        if (lane >= off) x += y;
    }
    if (lane == 63) wsum[wid] = x;
    __syncthreads();
    if (wid == 0) {
        int s = (lane < 16) ? wsum[lane] : 0;
#pragma unroll
        for (int off = 1; off < 16; off <<= 1) {
            int y = __shfl_up(s, off, 64);
            if (lane >= off) s += y;
        }
        if (lane < 16) wsum[lane] = s;
    }
    __syncthreads();
    int incl = x + (wid > 0 ? wsum[wid - 1] : 0);
    if (i < n) tmp[i] = incl;
    if (t == 1023) bsum[blockIdx.x] = incl;
}

__global__ void k_scan2(const int* __restrict__ bsum, int* __restrict__ boff, int nb) {
    int t = threadIdx.x;
    int v = (t < nb) ? bsum[t] : 0;
    int x = v;
#pragma unroll
    for (int off = 1; off < 64; off <<= 1) {
        int y = __shfl_up(x, off, 64);
        if (t >= off) x += y;
    }
    if (t < nb) boff[t] = x - v;   // exclusive
}

__global__ __launch_bounds__(1024) void k_scan3(const int* __restrict__ deg,
                                                const int* __restrict__ tmp,
                                                const int* __restrict__ boff,
                                                int* __restrict__ rs,
                                                int* __restrict__ cursor, int n) {
    int i = blockIdx.x * 1024 + threadIdx.x;
    if (i == 0) rs[0] = 0;
    if (i < n) {
        int v = tmp[i] + boff[blockIdx.x];
        rs[i + 1] = v;
        cursor[i] = v - deg[i];
    }
}

__global__ void k_fill(const int* __restrict__ src, const int* __restrict__ dst,
                       int* __restrict__ cursor, int* __restrict__ esrc, int E) {
    int e = blockIdx.x * blockDim.x + threadIdx.x;
    if (e < E) {
        int pos = atomicAdd(&cursor[dst[e]], 1);
        esrc[pos] = src[e];
    }
}

// ---------------- aggregate: out[n] = (relu?) P[n] + mean_nbr Q ----------------
__global__ __launch_bounds__(64) void k_agg(const float* __restrict__ PQ,
                                            const int* __restrict__ rs,
                                            const int* __restrict__ esrc,
                                            float* __restrict__ out, int ldout, int relu)
{
    int n = blockIdx.x, t = threadIdx.x;
    int s0 = rs[n], s1 = rs[n + 1];
    float a0 = 0.f, a1 = 0.f, a2 = 0.f, a3 = 0.f;
    int i = s0;
    for (; i + 4 <= s1; i += 4) {
        int e0 = esrc[i], e1 = esrc[i + 1], e2 = esrc[i + 2], e3 = esrc[i + 3];
        a0 += PQ[(size_t)e0 * 128 + 64 + t];
        a1 += PQ[(size_t)e1 * 128 + 64 + t];
        a2 += PQ[(size_t)e2 * 128 + 64 + t];
        a3 += PQ[(size_t)e3 * 128 + 64 + t];
    }
    for (; i < s1; ++i) a0 += PQ[(size_t)esrc[i] * 128 + 64 + t];
    float s = (a0 + a1) + (a2 + a3);
    float dg = (float)(s1 - s0);
    s /= fmaxf(dg, 1.f);
    float v = PQ[(size_t)n * 128 + t] + s;
    if (relu) v = fmaxf(v, 0.f);
    out[(size_t)n * ldout + t] = v;
}

extern "C" void kernel_launch(void* const* d_in, const int* in_sizes, int n_in,
                              void* d_out, int out_size, void* d_ws, size_t ws_size,
                              hipStream_t stream)
{
    const float* d_features = (const float*)d_in[0];
    const float* g_features = (const float*)d_in[1];
    const float* miRNA_dis  = (const float*)d_in[2];
    const float* gene_dis   = (const float*)d_in[3];
    const float* Wd  = (const float*)d_in[4];
    const float* bd  = (const float*)d_in[5];
    const float* Wg  = (const float*)d_in[6];
    const float* bg  = (const float*)d_in[7];
    const float* W1  = (const float*)d_in[8];
    const float* W4  = (const float*)d_in[9];
    const float* Ws1 = (const float*)d_in[10];
    const float* Wn1 = (const float*)d_in[11];
    const float* b1  = (const float*)d_in[12];
    const float* Ws2 = (const float*)d_in[13];
    const float* Wn2 = (const float*)d_in[14];
    const float* b2  = (const float*)d_in[15];
    const int* src = (const int*)d_in[16];
    const int* dst = (const int*)d_in[17];
    (void)in_sizes; (void)n_in; (void)out_size; (void)ws_size;

    char* ws = (char*)d_ws;
    float*  h0   = (float*)(ws + OFF_H0);
    float*  PQ   = (float*)(ws + OFF_PQ);
    float*  h1   = (float*)(ws + OFF_H1);   // [NTOT][64] compact
    int*    deg  = (int*)(ws + OFF_DEG);
    int*    rs   = (int*)(ws + OFF_RS);
    int*    cur  = (int*)(ws + OFF_CUR);
    int*    tmp  = (int*)(ws + OFF_TMP);
    int*    bsum = (int*)(ws + OFF_BSUM);
    int*    boff = (int*)(ws + OFF_BOFF);
    int*    esrc = (int*)(ws + OFF_ESRC);
    ushort* miT  = (ushort*)(ws + OFF_MIT);
    ushort* Bdis = (ushort*)(ws + OFF_BDIS);
    ushort* Bgen = (ushort*)(ws + OFF_BGEN);
    ushort* Bs1  = (ushort*)(ws + OFF_BS1);
    ushort* Bs2  = (ushort*)(ws + OFF_BS2);
    float*  Pd   = (float*)(ws + OFF_PD);
    float*  Pg   = (float*)(ws + OFF_PG);

    // ---- init ----
    hipMemsetAsync(deg, 0, (size_t)NTOT * 4, stream);

    // ---- transposes/converts/fragment-permutes + fused degree count ----
    TcvtIns ins;
    ins.p[0] = Wd;  ins.p[1] = W1;  ins.p[2] = Wg;  ins.p[3] = W4;
    ins.p[4] = miRNA_dis; ins.p[5] = Ws1; ins.p[6] = Wn1; ins.p[7] = Ws2; ins.p[8] = Wn2;
    k_tcvt_multi<<<11584 + 1563, 256, 0, stream>>>(ins, ws, dst, deg);

    // ---- CSR by dst (hierarchical scan) ----
    k_scan1<<<25, 1024, 0, stream>>>(deg, tmp, bsum, NTOT);
    k_scan2<<<1, 64, 0, stream>>>(bsum, boff, 25);
    k_scan3<<<25, 1024, 0, stream>>>(deg, tmp, boff, rs, cur, NTOT);
    k_fill<<<(EDG + 255) / 256, 256, 0, stream>>>(src, dst, cur, esrc, EDG);

    // ---- merged embedding GEMMs (gene blocks 0..312, dis 313..391; 5 splits) ----
    EmbOp opg = {g_features, 4395, 4395, 35, gene_dis, 5000, 5000, 40,
                 Bgen, 300, Pg, NGEN, 1};
    EmbOp opd = {d_features, 383, 383, 3, miT, 2048, 2048, 16,
                 Bdis, 76, Pd, NDIS, 2};
    gemm_st<true><<<dim3(392, 5), 256, 0, stream>>>(opg, opd, 313, nullptr);
    k_reduce<<<(NTOT * 128 + 255) / 256, 256, 0, stream>>>(Pd, Pg, bd, bg, h0);

    // ---- SAGE layer 1: PQ = h0 @ [Ws1|Wn1] (+b1 on P cols), aggregate ----
    EmbOp ops1 = {h0, 128, 128, 1, nullptr, 0, 0, 0, Bs1, 4, PQ, NTOT, 0};
    gemm_st<false><<<dim3(391, 1), 256, 0, stream>>>(ops1, ops1, 391, b1);
    k_agg<<<NTOT, 64, 0, stream>>>(PQ, rs, esrc, h1, 64, 1);

    // ---- SAGE layer 2 (h1 compact [NTOT][64], K1=64 via boundary guards) ----
    EmbOp ops2 = {h1, 64, 64, 1, nullptr, 0, 0, 0, Bs2, 4, PQ, NTOT, 0};
    gemm_st<false><<<dim3(391, 1), 256, 0, stream>>>(ops2, ops2, 391, b2);
    k_agg<<<NTOT, 64, 0, stream>>>(PQ, rs, esrc, (float*)d_out, 64, 0);
}

// Round 17
// 351.602 us; speedup vs baseline: 1.2033x; 1.2033x over previous
//
#include <hip/hip_runtime.h>

#define NDIS 5000
#define NGEN 20000
#define NTOT 25000
#define EDG  400000

typedef __attribute__((ext_vector_type(8))) short short8;
typedef __attribute__((ext_vector_type(4))) float f32x4;
typedef __attribute__((ext_vector_type(4), aligned(4))) float f32x4u;
typedef __attribute__((ext_vector_type(4))) unsigned int uint4v;
typedef __attribute__((ext_vector_type(2))) unsigned int uint2v;
typedef __attribute__((ext_vector_type(2), aligned(4))) unsigned int uint2a;

// ---------------- workspace layout ----------------
constexpr size_t AL(size_t x) { return (x + 255) & ~(size_t)255; }
constexpr size_t OFF_H0   = 0;
constexpr size_t OFF_PQ   = AL(OFF_H0  + (size_t)NTOT * 128 * 4);
constexpr size_t OFF_H1   = AL(OFF_PQ  + (size_t)NTOT * 128 * 4);
constexpr size_t OFF_DEG  = AL(OFF_H1  + (size_t)NTOT * 128 * 4);
constexpr size_t OFF_RS   = AL(OFF_DEG + (size_t)NTOT * 4);
constexpr size_t OFF_CUR  = AL(OFF_RS  + (size_t)(NTOT + 1) * 4);
constexpr size_t OFF_TMP  = AL(OFF_CUR + (size_t)NTOT * 4);
constexpr size_t OFF_BSUM = AL(OFF_TMP + (size_t)NTOT * 4);
constexpr size_t OFF_BOFF = AL(OFF_BSUM + 64 * 4);
constexpr size_t OFF_ESRC = AL(OFF_BOFF + 64 * 4);
constexpr size_t OFF_MIT  = AL(OFF_ESRC + (size_t)EDG * 4);
constexpr size_t OFF_BDIS = AL(OFF_MIT + (size_t)5000 * 2048 * 2);   // KT=76
constexpr size_t OFF_BGEN = AL(OFF_BDIS + (size_t)8 * 76 * 512 * 2); // KT=300
constexpr size_t OFF_BS1  = AL(OFF_BGEN + (size_t)8 * 300 * 512 * 2);
constexpr size_t OFF_BS2  = AL(OFF_BS1 + (size_t)8 * 4 * 512 * 2);

__device__ __forceinline__ ushort f2bf(float f) {
    unsigned u = __float_as_uint(f);
    u += 0x7fffu + ((u >> 16) & 1u);
    return (ushort)(u >> 16);
}

__device__ __forceinline__ unsigned cvtpk(float a, float b) {
    unsigned r;
    asm("v_cvt_pk_bf16_f32 %0, %1, %2" : "=v"(r) : "v"(a), "v"(b));
    return r;
}

__device__ __forceinline__ void MFMA(f32x4& d, short8 a, short8 b) {
    asm volatile("v_mfma_f32_16x16x32_bf16 %0, %1, %2, %0"
                 : "+v"(d) : "v"(a), "v"(b));
}

// ---------------- multi-descriptor transpose/convert/permute (+deg count) ----------------
struct TcvtIns { const float* p[9]; };

__global__ __launch_bounds__(256) void k_tcvt_multi(TcvtIns ins, char* ws,
                                                    const int* __restrict__ dst,
                                                    int* __restrict__ deg)
{
    constexpr int   TR[9]   = {383, 2000, 4395, 5000, 2000, 128, 128, 64, 64};
    constexpr int   TC[9]   = {128, 128, 128, 128, 5000, 64, 64, 64, 64};
    constexpr int   TKT[9]  = {76, 76, 300, 300, 2048 /*ld*/, 4, 4, 4, 4};
    constexpr int   TKO[9]  = {0, 12, 0, 140, 0, 0, 0, 0, 0};
    constexpr int   TRP[9]  = {384, 2048, 4480, 5120, 2048, 128, 128, 128, 128};
    constexpr int   TNOFF[9]= {0, 0, 0, 0, 0, 0, 64, 0, 64};
    constexpr int   TMODE[9]= {1, 1, 1, 1, 0, 1, 1, 1, 1};
    constexpr float TSC[9]  = {0.9f, 0.1f, 0.9f, 0.1f, 1.f, 1.f, 1.f, 1.f, 1.f};
    constexpr size_t TOUT[9]= {OFF_BDIS, OFF_BDIS, OFF_BGEN, OFF_BGEN, OFF_MIT,
                               OFF_BS1, OFF_BS1, OFF_BS2, OFF_BS2};
    constexpr int TNBX[9]   = {4, 4, 4, 4, 157, 2, 2, 2, 2};
    constexpr int PRE[10]   = {0, 48, 304, 864, 1504, 11552, 11560, 11568, 11576, 11584};

    int bid = blockIdx.x;
    if (bid >= 11584) {                       // fused degree count
        int e = (bid - 11584) * 256 + threadIdx.x;
        if (e < EDG) atomicAdd(&deg[dst[e]], 1);
        return;
    }
    int d = 0;
#pragma unroll
    for (int q = 1; q < 9; ++q) if (bid >= PRE[q]) d = q;
    int local = bid - PRE[d];
    int bx = local % TNBX[d], by = local / TNBX[d];
    const int R = TR[d], C = TC[d], KT = TKT[d], KO = TKO[d];
    const int Rp = TRP[d], noff = TNOFF[d];
    const float scale = TSC[d];
    const float* in = ins.p[d];
    ushort* out = (ushort*)(ws + TOUT[d]);

    __shared__ float t[32][33];
    int tx = threadIdx.x & 31, ty = threadIdx.x >> 5;
    int c0 = bx * 32, r0 = by * 32;
#pragma unroll
    for (int j = 0; j < 4; ++j) {
        int r = r0 + ty + j * 8, c = c0 + tx;
        t[ty + j * 8][tx] = (r < R && c < C) ? in[(size_t)r * C + c] : 0.f;
    }
    __syncthreads();
#pragma unroll
    for (int j = 0; j < 4; ++j) {
        int c = c0 + ty + j * 8, r = r0 + tx;
        if (c >= C || r >= Rp) continue;
        ushort bv = f2bf(scale * t[tx][ty + j * 8]);
        if (TMODE[d] == 0) {
            out[(size_t)c * KT + r] = bv;
        } else {
            int n = noff + c, k = r;
            out[(size_t)((n >> 4) * KT + KO + (k >> 5)) * 512 +
                ((k >> 3) & 3) * 128 + (n & 15) * 8 + (k & 7)] = bv;
        }
    }
}

// ---------------- streaming MFMA GEMM, 512B-run A reads, single bf16 A ----------------
// C[M,128] (+)= [A1 f32 (nst1 supertiles of 128k) | A2 (nst2 supertiles)] @ B
// Bf = bf16 fragment tensor (KT = 4*(nst1+nst2) k32-tiles, pads zero).
// A2MODE: 0 none, 1 f32, 2 bf16. Split-K over gridDim.y (ATOMIC).
// Boundary handling: row-local clamp + per-element k-guards on boundary
// supertiles only (R11 fix). launch_bounds(256,2): (256,4) spilled (R13);
// runtime op-select regressed 230->300us (R16) -> keep template params.
template<int A2MODE, bool ATOMIC>
__global__ __launch_bounds__(256, 2) void gemm_st(
    const float* __restrict__ A1, int lda1, int K1, int nst1,
    const void* __restrict__ A2v, int lda2, int K2, int nst2,
    const ushort* __restrict__ Bf, int KT,
    float* __restrict__ C, int M, const float* __restrict__ bias)
{
    __shared__ ushort lds0[64 * 128];
    __shared__ ushort lds1[64 * 128];
    const int tid  = threadIdx.x;
    const int lane = tid & 63;
    const int w    = tid >> 6;
    const int fr = lane & 15, kq = lane >> 4;
    const int bm0 = blockIdx.x * 64;

    const int NSTT = nst1 + nst2;
    const int per = (NSTT + gridDim.y - 1) / gridDim.y;
    const int s0 = blockIdx.y * per;
    const int s1 = min(NSTT, s0 + per);
    const int NT = s1 - s0;
    if (NT <= 0) return;

    f32x4 acc[4][2];
#pragma unroll
    for (int i = 0; i < 4; ++i) { acc[i][0] = {0.f,0.f,0.f,0.f}; acc[i][1] = {0.f,0.f,0.f,0.f}; }

    uint4v faA[8], faB[8];
    short8 Breg0[4][2], Breg1[4][2];

    const int srow = w * 16 + (lane >> 5);   // stage row base (this thread)
    const int scol = lane & 31;              // 4 k-values per thread

    auto issueA = [&](int stg, uint4v* fa) {
        const bool r1 = (A2MODE == 0) || (stg < nst1);
#pragma unroll
        for (int i = 0; i < 8; ++i) {
            int r = bm0 + srow + i * 2;
            if (r > M - 1) r = M - 1;        // row-local clamp (value discarded in epilogue)
            if (r1) {
                const int kb = stg << 7;
                const int k = kb + scol * 4;
                const float* p = A1 + (size_t)r * lda1 + k;
                if (kb + 128 <= K1) {
                    fa[i] = __builtin_bit_cast(uint4v, *(const f32x4u*)p);
                } else {                      // boundary supertile: per-element guard
                    f32x4 v;
#pragma unroll
                    for (int e = 0; e < 4; ++e) v[e] = (k + e < K1) ? p[e] : 0.f;
                    fa[i] = __builtin_bit_cast(uint4v, v);
                }
            } else if (A2MODE == 1) {
                const int kb = (stg - nst1) << 7;
                const int kc = kb + scol * 4;
                const float* p = (const float*)A2v + (size_t)r * lda2 + kc;
                if (kb + 128 <= K2) {
                    fa[i] = __builtin_bit_cast(uint4v, *(const f32x4u*)p);
                } else {
                    f32x4 v;
#pragma unroll
                    for (int e = 0; e < 4; ++e) v[e] = (kc + e < K2) ? p[e] : 0.f;
                    fa[i] = __builtin_bit_cast(uint4v, v);
                }
            } else {                          // bf16 A2: K2 multiple of 128, always full
                const int kc = ((stg - nst1) << 7) + scol * 4;
                uint2a v = *(const uint2a*)((const ushort*)A2v + (size_t)r * lda2 + kc);
                fa[i][0] = v[0]; fa[i][1] = v[1];
            }
        }
    };
    auto issueB = [&](int stg, short8 (*BR)[2]) {
#pragma unroll
        for (int ks = 0; ks < 4; ++ks)
#pragma unroll
            for (int nf = 0; nf < 2; ++nf)
                BR[ks][nf] = *(const short8*)(
                    Bf + (size_t)((w * 2 + nf) * KT + stg * 4 + ks) * 512 + lane * 8);
    };
    auto writeT = [&](int stg, const uint4v* fa, ushort* buf) {
        const bool cvt = (A2MODE != 2) || (stg < nst1);
        const int G = scol >> 1, h = lane & 1;
#pragma unroll
        for (int i = 0; i < 8; ++i) {
            int r = srow + i * 2;
            const size_t off = (size_t)r * 256 + ((G ^ (r & 7)) << 4) + h * 8;
            uint2v d;
            if (cvt) {
                f32x4 v = __builtin_bit_cast(f32x4, fa[i]);
                d[0] = cvtpk(v[0], v[1]);
                d[1] = cvtpk(v[2], v[3]);
            } else {
                d[0] = fa[i][0]; d[1] = fa[i][1];
            }
            *(uint2v*)((char*)buf + off) = d;
        }
    };

#define PHASE(T, BR, LDSC, FAW, LDSW)                                        \
    {                                                                        \
        const int x7 = fr & 7;                                               \
        _Pragma("unroll")                                                    \
        for (int ks = 0; ks < 4; ++ks) {                                     \
            short8 af[4];                                                    \
            _Pragma("unroll")                                                \
            for (int mf = 0; mf < 4; ++mf)                                   \
                af[mf] = *(const short8*)&LDSC[fr * 128 + mf * 2048 +        \
                                              (((ks * 4 + kq) ^ x7) << 3)];  \
            _Pragma("unroll")                                                \
            for (int mf = 0; mf < 4; ++mf) {                                 \
                MFMA(acc[mf][0], af[mf], BR[ks][0]);                         \
                MFMA(acc[mf][1], af[mf], BR[ks][1]);                         \
            }                                                                \
        }                                                                    \
        if ((T) + 2 < NT) issueB(s0 + (T) + 2, BR);                          \
        __builtin_amdgcn_s_barrier();                                        \
        if ((T) + 1 < NT) {                                                  \
            writeT(s0 + (T) + 1, FAW, LDSW);                                 \
            if ((T) + 3 < NT) issueA(s0 + (T) + 3, FAW);                     \
            asm volatile("s_waitcnt lgkmcnt(0)" ::: "memory");               \
            __builtin_amdgcn_s_barrier();                                    \
        }                                                                    \
    }

    // prologue
    issueA(s0, faA); issueB(s0, Breg0);
    if (NT > 1) { issueA(s0 + 1, faB); issueB(s0 + 1, Breg1); }
    writeT(s0, faA, lds0);
    if (NT > 2) issueA(s0 + 2, faA);
    asm volatile("s_waitcnt lgkmcnt(0)" ::: "memory");
    __builtin_amdgcn_s_barrier();

    for (int t = 0; t < NT; t += 2) {
        PHASE(t, Breg0, lds0, faB, lds1);
        if (t + 1 < NT) PHASE(t + 1, Breg1, lds1, faA, lds0);
    }
#undef PHASE

    asm volatile("s_nop 7\n\ts_nop 7\n\ts_nop 7" ::: "memory");
#pragma unroll
    for (int mf = 0; mf < 4; ++mf)
#pragma unroll
        for (int nf = 0; nf < 2; ++nf)
#pragma unroll
            for (int r = 0; r < 4; ++r) {
                int row = bm0 + mf * 16 + kq * 4 + r;
                if (row < M) {
                    int col = w * 32 + nf * 16 + fr;
                    if (ATOMIC) {
                        atomicAdd(&C[(size_t)row * 128 + col], acc[mf][nf][r]);
                    } else {
                        float v = acc[mf][nf][r];
                        if (col < 64) v += bias[col];
                        C[(size_t)row * 128 + col] = v;
                    }
                }
            }
}

// ---------------- h0 init with scaled bias ----------------
__global__ void k_binit(float* __restrict__ h0, const float* __restrict__ bd,
                        const float* __restrict__ bg) {
    int i = blockIdx.x * 256 + threadIdx.x;
    if (i >= NTOT * 128) return;
    int col = i & 127;
    h0[i] = 0.9f * ((i >> 7) < NDIS ? bd[col] : bg[col]);
}

// ---------------- hierarchical CSR scan ----------------
__global__ __launch_bounds__(1024) void k_scan1(const int* __restrict__ deg,
                                                int* __restrict__ tmp,
                                                int* __restrict__ bsum, int n) {
    __shared__ int wsum[16];
    int t = threadIdx.x, lane = t & 63, wid = t >> 6;
    int i = blockIdx.x * 1024 + t;
    int v = (i < n) ? deg[i] : 0;
    int x = v;
#pragma unroll
    for (int off = 1; off < 64; off <<= 1) {
        int y = __shfl_up(x, off, 64);
        if (lane >= off) x += y;
    }
    if (lane == 63) wsum[wid] = x;
    __syncthreads();
    if (wid == 0) {
        int s = (lane < 16) ? wsum[lane] : 0;
#pragma unroll
        for (int off = 1; off < 16; off <<= 1) {
            int y = __shfl_up(s, off, 64);
            if (lane >= off) s += y;
        }
        if (lane < 16) wsum[lane] = s;
    }
    __syncthreads();
    int incl = x + (wid > 0 ? wsum[wid - 1] : 0);
    if (i < n) tmp[i] = incl;
    if (t == 1023) bsum[blockIdx.x] = incl;
}

__global__ void k_scan2(const int* __restrict__ bsum, int* __restrict__ boff, int nb) {
    int t = threadIdx.x;
    int v = (t < nb) ? bsum[t] : 0;
    int x = v;
#pragma unroll
    for (int off = 1; off < 64; off <<= 1) {
        int y = __shfl_up(x, off, 64);
        if (t >= off) x += y;
    }
    if (t < nb) boff[t] = x - v;   // exclusive
}

__global__ __launch_bounds__(1024) void k_scan3(const int* __restrict__ deg,
                                                const int* __restrict__ tmp,
                                                const int* __restrict__ boff,
                                                int* __restrict__ rs,
                                                int* __restrict__ cursor, int n) {
    int i = blockIdx.x * 1024 + threadIdx.x;
    if (i == 0) rs[0] = 0;
    if (i < n) {
        int v = tmp[i] + boff[blockIdx.x];
        rs[i + 1] = v;
        cursor[i] = v - deg[i];
    }
}

__global__ void k_fill(const int* __restrict__ src, const int* __restrict__ dst,
                       int* __restrict__ cursor, int* __restrict__ esrc, int E) {
    int e = blockIdx.x * blockDim.x + threadIdx.x;
    if (e < E) {
        int pos = atomicAdd(&cursor[dst[e]], 1);
        esrc[pos] = src[e];
    }
}

// ---------------- aggregate: out[n] = (relu?) P[n] + mean_nbr Q ----------------
__global__ __launch_bounds__(64) void k_agg(const float* __restrict__ PQ,
                                            const int* __restrict__ rs,
                                            const int* __restrict__ esrc,
                                            float* __restrict__ out, int ldout, int relu)
{
    int n = blockIdx.x, t = threadIdx.x;
    int s0 = rs[n], s1 = rs[n + 1];
    float a0 = 0.f, a1 = 0.f, a2 = 0.f, a3 = 0.f;
    int i = s0;
    for (; i + 4 <= s1; i += 4) {
        int e0 = esrc[i], e1 = esrc[i + 1], e2 = esrc[i + 2], e3 = esrc[i + 3];
        a0 += PQ[(size_t)e0 * 128 + 64 + t];
        a1 += PQ[(size_t)e1 * 128 + 64 + t];
        a2 += PQ[(size_t)e2 * 128 + 64 + t];
        a3 += PQ[(size_t)e3 * 128 + 64 + t];
    }
    for (; i < s1; ++i) a0 += PQ[(size_t)esrc[i] * 128 + 64 + t];
    float s = (a0 + a1) + (a2 + a3);
    float dg = (float)(s1 - s0);
    s /= fmaxf(dg, 1.f);
    float v = PQ[(size_t)n * 128 + t] + s;
    if (relu) v = fmaxf(v, 0.f);
    out[(size_t)n * ldout + t] = v;
}

extern "C" void kernel_launch(void* const* d_in, const int* in_sizes, int n_in,
                              void* d_out, int out_size, void* d_ws, size_t ws_size,
                              hipStream_t stream)
{
    const float* d_features = (const float*)d_in[0];
    const float* g_features = (const float*)d_in[1];
    const float* miRNA_dis  = (const float*)d_in[2];
    const float* gene_dis   = (const float*)d_in[3];
    const float* Wd  = (const float*)d_in[4];
    const float* bd  = (const float*)d_in[5];
    const float* Wg  = (const float*)d_in[6];
    const float* bg  = (const float*)d_in[7];
    const float* W1  = (const float*)d_in[8];
    const float* W4  = (const float*)d_in[9];
    const float* Ws1 = (const float*)d_in[10];
    const float* Wn1 = (const float*)d_in[11];
    const float* b1  = (const float*)d_in[12];
    const float* Ws2 = (const float*)d_in[13];
    const float* Wn2 = (const float*)d_in[14];
    const float* b2  = (const float*)d_in[15];
    const int* src = (const int*)d_in[16];
    const int* dst = (const int*)d_in[17];
    (void)in_sizes; (void)n_in; (void)out_size; (void)ws_size;

    char* ws = (char*)d_ws;
    float*  h0   = (float*)(ws + OFF_H0);
    float*  PQ   = (float*)(ws + OFF_PQ);
    float*  h1   = (float*)(ws + OFF_H1);   // [NTOT][128], cols 64..128 zero
    int*    deg  = (int*)(ws + OFF_DEG);
    int*    rs   = (int*)(ws + OFF_RS);
    int*    cur  = (int*)(ws + OFF_CUR);
    int*    tmp  = (int*)(ws + OFF_TMP);
    int*    bsum = (int*)(ws + OFF_BSUM);
    int*    boff = (int*)(ws + OFF_BOFF);
    int*    esrc = (int*)(ws + OFF_ESRC);
    ushort* miT  = (ushort*)(ws + OFF_MIT);
    ushort* Bdis = (ushort*)(ws + OFF_BDIS);
    ushort* Bgen = (ushort*)(ws + OFF_BGEN);
    ushort* Bs1  = (ushort*)(ws + OFF_BS1);
    ushort* Bs2  = (ushort*)(ws + OFF_BS2);

    // ---- init ----
    hipMemsetAsync(deg, 0, (size_t)NTOT * 4, stream);
    hipMemsetAsync(h1, 0, (size_t)NTOT * 128 * 4, stream);

    // ---- transposes/converts/fragment-permutes + fused degree count ----
    TcvtIns ins;
    ins.p[0] = Wd;  ins.p[1] = W1;  ins.p[2] = Wg;  ins.p[3] = W4;
    ins.p[4] = miRNA_dis; ins.p[5] = Ws1; ins.p[6] = Wn1; ins.p[7] = Ws2; ins.p[8] = Wn2;
    k_tcvt_multi<<<11584 + 1563, 256, 0, stream>>>(ins, ws, dst, deg);

    // ---- CSR by dst (hierarchical scan) ----
    k_scan1<<<25, 1024, 0, stream>>>(deg, tmp, bsum, NTOT);
    k_scan2<<<1, 64, 0, stream>>>(bsum, boff, 25);
    k_scan3<<<25, 1024, 0, stream>>>(deg, tmp, boff, rs, cur, NTOT);
    k_fill<<<(EDG + 255) / 256, 256, 0, stream>>>(src, dst, cur, esrc, EDG);

    // ---- h0 = 0.9*bias, then embedding GEMMs (atomic, split-K; R14 config) ----
    k_binit<<<(NTOT * 128 + 255) / 256, 256, 0, stream>>>(h0, bd, bg);
    gemm_st<2, true><<<dim3(79, 5), 256, 0, stream>>>(
        d_features, 383, 383, 3,
        miT, 2048, 2048, 16, Bdis, 76, h0, NDIS, nullptr);
    gemm_st<1, true><<<dim3(313, 4), 256, 0, stream>>>(
        g_features, 4395, 4395, 35,
        gene_dis, 5000, 5000, 40, Bgen, 300,
        h0 + (size_t)NDIS * 128, NGEN, nullptr);

    // ---- SAGE layer 1: PQ = h0 @ [Ws1|Wn1] (+b1 on P cols), aggregate ----
    gemm_st<0, false><<<dim3(391, 1), 256, 0, stream>>>(
        h0, 128, 128, 1, nullptr, 0, 0, 0, Bs1, 4, PQ, NTOT, b1);
    k_agg<<<NTOT, 64, 0, stream>>>(PQ, rs, esrc, h1, 128, 1);

    // ---- SAGE layer 2 ----
    gemm_st<0, false><<<dim3(391, 1), 256, 0, stream>>>(
        h1, 128, 128, 1, nullptr, 0, 0, 0, Bs2, 4, PQ, NTOT, b2);
    k_agg<<<NTOT, 64, 0, stream>>>(PQ, rs, esrc, (float*)d_out, 64, 0);
}

// Round 18
// 351.411 us; speedup vs baseline: 1.2040x; 1.0005x over previous
//
#include <hip/hip_runtime.h>

#define NDIS 5000
#define NGEN 20000
#define NTOT 25000
#define EDG  400000

typedef __attribute__((ext_vector_type(8))) short short8;
typedef __attribute__((ext_vector_type(4))) float f32x4;
typedef __attribute__((ext_vector_type(4), aligned(4))) float f32x4u;
typedef __attribute__((ext_vector_type(4))) unsigned int uint4v;
typedef __attribute__((ext_vector_type(2))) unsigned int uint2v;
typedef __attribute__((ext_vector_type(2), aligned(4))) unsigned int uint2a;

// ---------------- workspace layout ----------------
constexpr size_t AL(size_t x) { return (x + 255) & ~(size_t)255; }
constexpr size_t OFF_H0   = 0;
constexpr size_t OFF_PQ   = AL(OFF_H0  + (size_t)NTOT * 128 * 4);
constexpr size_t OFF_H1   = AL(OFF_PQ  + (size_t)NTOT * 128 * 4);
constexpr size_t OFF_DEG  = AL(OFF_H1  + (size_t)NTOT * 128 * 4);
constexpr size_t OFF_RS   = AL(OFF_DEG + (size_t)NTOT * 4);
constexpr size_t OFF_CUR  = AL(OFF_RS  + (size_t)(NTOT + 1) * 4);
constexpr size_t OFF_TMP  = AL(OFF_CUR + (size_t)NTOT * 4);
constexpr size_t OFF_BSUM = AL(OFF_TMP + (size_t)NTOT * 4);
constexpr size_t OFF_BOFF = AL(OFF_BSUM + 64 * 4);
constexpr size_t OFF_ESRC = AL(OFF_BOFF + 64 * 4);
constexpr size_t OFF_MIT  = AL(OFF_ESRC + (size_t)EDG * 4);
constexpr size_t OFF_BDIS = AL(OFF_MIT + (size_t)5000 * 2048 * 2);   // KT=80 tiles
constexpr size_t OFF_BGEN = AL(OFF_BDIS + (size_t)8 * 80 * 512 * 2); // KT=304 tiles
constexpr size_t OFF_BS1  = AL(OFF_BGEN + (size_t)8 * 304 * 512 * 2);
constexpr size_t OFF_BS2  = AL(OFF_BS1 + (size_t)8 * 4 * 512 * 2);

__device__ __forceinline__ ushort f2bf(float f) {
    unsigned u = __float_as_uint(f);
    u += 0x7fffu + ((u >> 16) & 1u);
    return (ushort)(u >> 16);
}

__device__ __forceinline__ unsigned cvtpk(float a, float b) {
    unsigned r;
    asm("v_cvt_pk_bf16_f32 %0, %1, %2" : "=v"(r) : "v"(a), "v"(b));
    return r;
}

__device__ __forceinline__ void MFMA(f32x4& d, short8 a, short8 b) {
    asm volatile("v_mfma_f32_16x16x32_bf16 %0, %1, %2, %0"
                 : "+v"(d) : "v"(a), "v"(b));
}

// ---------------- multi-descriptor transpose/convert/permute (+deg count) ----------------
struct TcvtIns { const float* p[9]; };

__global__ __launch_bounds__(256) void k_tcvt_multi(TcvtIns ins, char* ws,
                                                    const int* __restrict__ dst,
                                                    int* __restrict__ deg)
{
    constexpr int   TR[9]   = {383, 2000, 4395, 5000, 2000, 128, 128, 64, 64};
    constexpr int   TC[9]   = {128, 128, 128, 128, 5000, 64, 64, 64, 64};
    constexpr int   TKT[9]  = {80, 80, 304, 304, 2048 /*ld*/, 4, 4, 4, 4};
    constexpr int   TKO[9]  = {0, 16, 0, 144, 0, 0, 0, 0, 0};
    constexpr int   TRP[9]  = {512, 2048, 4608, 5120, 2048, 128, 128, 128, 128};
    constexpr int   TNOFF[9]= {0, 0, 0, 0, 0, 0, 64, 0, 64};
    constexpr int   TMODE[9]= {1, 1, 1, 1, 0, 1, 1, 1, 1};
    constexpr float TSC[9]  = {0.9f, 0.1f, 0.9f, 0.1f, 1.f, 1.f, 1.f, 1.f, 1.f};
    constexpr size_t TOUT[9]= {OFF_BDIS, OFF_BDIS, OFF_BGEN, OFF_BGEN, OFF_MIT,
                               OFF_BS1, OFF_BS1, OFF_BS2, OFF_BS2};
    constexpr int TNBX[9]   = {4, 4, 4, 4, 157, 2, 2, 2, 2};
    constexpr int PRE[10]   = {0, 64, 320, 896, 1536, 11584, 11592, 11600, 11608, 11616};

    int bid = blockIdx.x;
    if (bid >= 11616) {                       // fused degree count
        int e = (bid - 11616) * 256 + threadIdx.x;
        if (e < EDG) atomicAdd(&deg[dst[e]], 1);
        return;
    }
    int d = 0;
#pragma unroll
    for (int q = 1; q < 9; ++q) if (bid >= PRE[q]) d = q;
    int local = bid - PRE[d];
    int bx = local % TNBX[d], by = local / TNBX[d];
    const int R = TR[d], C = TC[d], KT = TKT[d], KO = TKO[d];
    const int Rp = TRP[d], noff = TNOFF[d];
    const float scale = TSC[d];
    const float* in = ins.p[d];
    ushort* out = (ushort*)(ws + TOUT[d]);

    __shared__ float t[32][33];
    int tx = threadIdx.x & 31, ty = threadIdx.x >> 5;
    int c0 = bx * 32, r0 = by * 32;
#pragma unroll
    for (int j = 0; j < 4; ++j) {
        int r = r0 + ty + j * 8, c = c0 + tx;
        t[ty + j * 8][tx] = (r < R && c < C) ? in[(size_t)r * C + c] : 0.f;
    }
    __syncthreads();
#pragma unroll
    for (int j = 0; j < 4; ++j) {
        int c = c0 + ty + j * 8, r = r0 + tx;
        if (c >= C || r >= Rp) continue;
        ushort bv = f2bf(scale * t[tx][ty + j * 8]);
        if (TMODE[d] == 0) {
            out[(size_t)c * KT + r] = bv;
        } else {
            int n = noff + c, k = r;
            out[(size_t)((n >> 4) * KT + KO + (k >> 5)) * 512 +
                ((k >> 3) & 3) * 128 + (n & 15) * 8 + (k & 7)] = bv;
        }
    }
}

// ---------------- streaming MFMA GEMM: BK=NKS*32, 1KB-run A reads ----------------
// C[M,128] (+)= [A1 f32 (nst1 supertiles of NKS*32 k) | A2 (nst2)] @ Bf
// Bf = bf16 fragment tensor (KT tiles of 32k; pads zero). Single-LDS-buffer,
// single fa/Breg pipeline: writeT(t); issueA(t+1); barrier; compute(t);
// issueB(t+1); barrier. Raw barriers keep loads in flight.
// Row-local clamp + per-element k-guards on boundary supertiles (R11 fix).
// launch_bounds(256,2): (256,4) spilled at R13.
template<int A2MODE, bool ATOMIC, int NKS>
__global__ __launch_bounds__(256, 2) void gemm_st(
    const float* __restrict__ A1, int lda1, int K1, int nst1,
    const void* __restrict__ A2v, int lda2, int K2, int nst2,
    const ushort* __restrict__ Bf, int KT,
    float* __restrict__ C, int M, const float* __restrict__ bias)
{
    constexpr int SUP = NKS * 32;       // k per supertile
    constexpr int JPR = NKS / 4;        // 512B instrs per row per phase
    __shared__ ushort lds[64 * SUP];    // 64 rows x SUP bf16 (swizzled)
    const int tid  = threadIdx.x;
    const int lane = tid & 63;
    const int w    = tid >> 6;
    const int fr = lane & 15, kq = lane >> 4;
    const int bm0 = blockIdx.x * 64;
    const int grp  = tid >> 5;          // 0..7 staging row group
    const int scol = lane & 31;

    const int NSTT = nst1 + nst2;
    const int per = (NSTT + gridDim.y - 1) / gridDim.y;
    const int s0 = blockIdx.y * per;
    const int s1 = min(NSTT, s0 + per);
    if (s0 >= s1) return;

    f32x4 acc[4][2];
#pragma unroll
    for (int i = 0; i < 4; ++i) { acc[i][0] = {0.f,0.f,0.f,0.f}; acc[i][1] = {0.f,0.f,0.f,0.f}; }

    uint4v fa[8 * JPR];
    short8 Br[NKS][2];

    auto issueA = [&](int stg) {
        const bool r1 = (A2MODE == 0) || (stg < nst1);
#pragma unroll
        for (int i = 0; i < 8; ++i) {
            int r = bm0 + grp + i * 8;
            if (r > M - 1) r = M - 1;   // row-local clamp (discarded in epilogue)
            if (r1) {
                const int kb = stg * SUP;
#pragma unroll
                for (int j = 0; j < JPR; ++j) {
                    const int k = kb + j * 128 + scol * 4;
                    const float* p = A1 + (size_t)r * lda1 + k;
                    if (kb + SUP <= K1) {
                        fa[i * JPR + j] = __builtin_bit_cast(uint4v, *(const f32x4u*)p);
                    } else {            // boundary supertile: per-element guard
                        f32x4 v;
#pragma unroll
                        for (int e = 0; e < 4; ++e) v[e] = (k + e < K1) ? p[e] : 0.f;
                        fa[i * JPR + j] = __builtin_bit_cast(uint4v, v);
                    }
                }
            } else if (A2MODE == 1) {
                const int kb = (stg - nst1) * SUP;
#pragma unroll
                for (int j = 0; j < JPR; ++j) {
                    const int kc = kb + j * 128 + scol * 4;
                    const float* p = (const float*)A2v + (size_t)r * lda2 + kc;
                    if (kb + SUP <= K2) {
                        fa[i * JPR + j] = __builtin_bit_cast(uint4v, *(const f32x4u*)p);
                    } else {
                        f32x4 v;
#pragma unroll
                        for (int e = 0; e < 4; ++e) v[e] = (kc + e < K2) ? p[e] : 0.f;
                        fa[i * JPR + j] = __builtin_bit_cast(uint4v, v);
                    }
                }
            } else {                    // bf16 A2: K2 multiple of SUP, always full
                const int kb = (stg - nst1) * SUP;
#pragma unroll
                for (int j = 0; j < JPR; ++j) {
                    const int kc = kb + j * 128 + scol * 4;
                    uint2a v = *(const uint2a*)((const ushort*)A2v + (size_t)r * lda2 + kc);
                    fa[i * JPR + j][0] = v[0];
                    fa[i * JPR + j][1] = v[1];
                }
            }
        }
    };
    auto issueB = [&](int stg) {
#pragma unroll
        for (int ks = 0; ks < NKS; ++ks)
#pragma unroll
            for (int nf = 0; nf < 2; ++nf)
                Br[ks][nf] = *(const short8*)(
                    Bf + (size_t)((w * 2 + nf) * KT + stg * NKS + ks) * 512 + lane * 8);
    };
    auto writeT = [&](int stg) {
        const bool cvt = (A2MODE != 2) || (stg < nst1);
#pragma unroll
        for (int i = 0; i < 8; ++i) {
            const int rL = grp + i * 8;
#pragma unroll
            for (int j = 0; j < JPR; ++j) {
                const int slot16 = (scol >> 1) + j * 16;
                const size_t off = (size_t)rL * (SUP * 2) +
                                   ((slot16 ^ (rL & 7)) << 4) + (scol & 1) * 8;
                uint2v d;
                if (cvt) {
                    f32x4 v = __builtin_bit_cast(f32x4, fa[i * JPR + j]);
                    d[0] = cvtpk(v[0], v[1]);
                    d[1] = cvtpk(v[2], v[3]);
                } else {
                    d[0] = fa[i * JPR + j][0];
                    d[1] = fa[i * JPR + j][1];
                }
                *(uint2v*)((char*)lds + off) = d;
            }
        }
    };
    auto compute = [&]() {
        const int x7 = fr & 7;
#pragma unroll
        for (int ks = 0; ks < NKS; ++ks) {
            short8 af[4];
#pragma unroll
            for (int mf = 0; mf < 4; ++mf)
                af[mf] = *(const short8*)((char*)lds +
                    (size_t)(mf * 16 + fr) * (SUP * 2) +
                    (((ks * 4 + kq) ^ x7) << 4));
#pragma unroll
            for (int mf = 0; mf < 4; ++mf) {
                MFMA(acc[mf][0], af[mf], Br[ks][0]);
                MFMA(acc[mf][1], af[mf], Br[ks][1]);
            }
        }
    };

    issueA(s0); issueB(s0);
    for (int t = s0; t < s1; ++t) {
        writeT(t);                                   // vmcnt waits on fa inside
        if (t + 1 < s1) issueA(t + 1);               // fa freed by writeT
        asm volatile("s_waitcnt lgkmcnt(0)" ::: "memory");
        __builtin_amdgcn_s_barrier();                // LDS ready
        compute();
        if (t + 1 < s1) issueB(t + 1);               // Br freed after last MFMA
        __builtin_amdgcn_s_barrier();                // all reads done before next write
    }

    asm volatile("s_nop 7\n\ts_nop 7\n\ts_nop 7" ::: "memory");
#pragma unroll
    for (int mf = 0; mf < 4; ++mf)
#pragma unroll
        for (int nf = 0; nf < 2; ++nf)
#pragma unroll
            for (int r = 0; r < 4; ++r) {
                int row = bm0 + mf * 16 + kq * 4 + r;
                if (row < M) {
                    int col = w * 32 + nf * 16 + fr;
                    if (ATOMIC) {
                        atomicAdd(&C[(size_t)row * 128 + col], acc[mf][nf][r]);
                    } else {
                        float v = acc[mf][nf][r];
                        if (col < 64) v += bias[col];
                        C[(size_t)row * 128 + col] = v;
                    }
                }
            }
}

// ---------------- h0 init with scaled bias ----------------
__global__ void k_binit(float* __restrict__ h0, const float* __restrict__ bd,
                        const float* __restrict__ bg) {
    int i = blockIdx.x * 256 + threadIdx.x;
    if (i >= NTOT * 128) return;
    int col = i & 127;
    h0[i] = 0.9f * ((i >> 7) < NDIS ? bd[col] : bg[col]);
}

// ---------------- hierarchical CSR scan ----------------
__global__ __launch_bounds__(1024) void k_scan1(const int* __restrict__ deg,
                                                int* __restrict__ tmp,
                                                int* __restrict__ bsum, int n) {
    __shared__ int wsum[16];
    int t = threadIdx.x, lane = t & 63, wid = t >> 6;
    int i = blockIdx.x * 1024 + t;
    int v = (i < n) ? deg[i] : 0;
    int x = v;
#pragma unroll
    for (int off = 1; off < 64; off <<= 1) {
        int y = __shfl_up(x, off, 64);
        if (lane >= off) x += y;
    }
    if (lane == 63) wsum[wid] = x;
    __syncthreads();
    if (wid == 0) {
        int s = (lane < 16) ? wsum[lane] : 0;
#pragma unroll
        for (int off = 1; off < 16; off <<= 1) {
            int y = __shfl_up(s, off, 64);
            if (lane >= off) s += y;
        }
        if (lane < 16) wsum[lane] = s;
    }
    __syncthreads();
    int incl = x + (wid > 0 ? wsum[wid - 1] : 0);
    if (i < n) tmp[i] = incl;
    if (t == 1023) bsum[blockIdx.x] = incl;
}

__global__ void k_scan2(const int* __restrict__ bsum, int* __restrict__ boff, int nb) {
    int t = threadIdx.x;
    int v = (t < nb) ? bsum[t] : 0;
    int x = v;
#pragma unroll
    for (int off = 1; off < 64; off <<= 1) {
        int y = __shfl_up(x, off, 64);
        if (t >= off) x += y;
    }
    if (t < nb) boff[t] = x - v;   // exclusive
}

__global__ __launch_bounds__(1024) void k_scan3(const int* __restrict__ deg,
                                                const int* __restrict__ tmp,
                                                const int* __restrict__ boff,
                                                int* __restrict__ rs,
                                                int* __restrict__ cursor, int n) {
    int i = blockIdx.x * 1024 + threadIdx.x;
    if (i == 0) rs[0] = 0;
    if (i < n) {
        int v = tmp[i] + boff[blockIdx.x];
        rs[i + 1] = v;
        cursor[i] = v - deg[i];
    }
}

__global__ void k_fill(const int* __restrict__ src, const int* __restrict__ dst,
                       int* __restrict__ cursor, int* __restrict__ esrc, int E) {
    int e = blockIdx.x * blockDim.x + threadIdx.x;
    if (e < E) {
        int pos = atomicAdd(&cursor[dst[e]], 1);
        esrc[pos] = src[e];
    }
}

// ---------------- aggregate: out[n] = (relu?) P[n] + mean_nbr Q ----------------
__global__ __launch_bounds__(64) void k_agg(const float* __restrict__ PQ,
                                            const int* __restrict__ rs,
                                            const int* __restrict__ esrc,
                                            float* __restrict__ out, int ldout, int relu)
{
    int n = blockIdx.x, t = threadIdx.x;
    int s0 = rs[n], s1 = rs[n + 1];
    float a0 = 0.f, a1 = 0.f, a2 = 0.f, a3 = 0.f;
    int i = s0;
    for (; i + 4 <= s1; i += 4) {
        int e0 = esrc[i], e1 = esrc[i + 1], e2 = esrc[i + 2], e3 = esrc[i + 3];
        a0 += PQ[(size_t)e0 * 128 + 64 + t];
        a1 += PQ[(size_t)e1 * 128 + 64 + t];
        a2 += PQ[(size_t)e2 * 128 + 64 + t];
        a3 += PQ[(size_t)e3 * 128 + 64 + t];
    }
    for (; i < s1; ++i) a0 += PQ[(size_t)esrc[i] * 128 + 64 + t];
    float s = (a0 + a1) + (a2 + a3);
    float dg = (float)(s1 - s0);
    s /= fmaxf(dg, 1.f);
    float v = PQ[(size_t)n * 128 + t] + s;
    if (relu) v = fmaxf(v, 0.f);
    out[(size_t)n * ldout + t] = v;
}

extern "C" void kernel_launch(void* const* d_in, const int* in_sizes, int n_in,
                              void* d_out, int out_size, void* d_ws, size_t ws_size,
                              hipStream_t stream)
{
    const float* d_features = (const float*)d_in[0];
    const float* g_features = (const float*)d_in[1];
    const float* miRNA_dis  = (const float*)d_in[2];
    const float* gene_dis   = (const float*)d_in[3];
    const float* Wd  = (const float*)d_in[4];
    const float* bd  = (const float*)d_in[5];
    const float* Wg  = (const float*)d_in[6];
    const float* bg  = (const float*)d_in[7];
    const float* W1  = (const float*)d_in[8];
    const float* W4  = (const float*)d_in[9];
    const float* Ws1 = (const float*)d_in[10];
    const float* Wn1 = (const float*)d_in[11];
    const float* b1  = (const float*)d_in[12];
    const float* Ws2 = (const float*)d_in[13];
    const float* Wn2 = (const float*)d_in[14];
    const float* b2  = (const float*)d_in[15];
    const int* src = (const int*)d_in[16];
    const int* dst = (const int*)d_in[17];
    (void)in_sizes; (void)n_in; (void)out_size; (void)ws_size;

    char* ws = (char*)d_ws;
    float*  h0   = (float*)(ws + OFF_H0);
    float*  PQ   = (float*)(ws + OFF_PQ);
    float*  h1   = (float*)(ws + OFF_H1);   // [NTOT][128], cols 64..128 zero
    int*    deg  = (int*)(ws + OFF_DEG);
    int*    rs   = (int*)(ws + OFF_RS);
    int*    cur  = (int*)(ws + OFF_CUR);
    int*    tmp  = (int*)(ws + OFF_TMP);
    int*    bsum = (int*)(ws + OFF_BSUM);
    int*    boff = (int*)(ws + OFF_BOFF);
    int*    esrc = (int*)(ws + OFF_ESRC);
    ushort* miT  = (ushort*)(ws + OFF_MIT);
    ushort* Bdis = (ushort*)(ws + OFF_BDIS);
    ushort* Bgen = (ushort*)(ws + OFF_BGEN);
    ushort* Bs1  = (ushort*)(ws + OFF_BS1);
    ushort* Bs2  = (ushort*)(ws + OFF_BS2);

    // ---- init ----
    hipMemsetAsync(deg, 0, (size_t)NTOT * 4, stream);
    hipMemsetAsync(h1, 0, (size_t)NTOT * 128 * 4, stream);

    // ---- transposes/converts/fragment-permutes + fused degree count ----
    TcvtIns ins;
    ins.p[0] = Wd;  ins.p[1] = W1;  ins.p[2] = Wg;  ins.p[3] = W4;
    ins.p[4] = miRNA_dis; ins.p[5] = Ws1; ins.p[6] = Wn1; ins.p[7] = Ws2; ins.p[8] = Wn2;
    k_tcvt_multi<<<11616 + 1563, 256, 0, stream>>>(ins, ws, dst, deg);

    // ---- CSR by dst (hierarchical scan) ----
    k_scan1<<<25, 1024, 0, stream>>>(deg, tmp, bsum, NTOT);
    k_scan2<<<1, 64, 0, stream>>>(bsum, boff, 25);
    k_scan3<<<25, 1024, 0, stream>>>(deg, tmp, boff, rs, cur, NTOT);
    k_fill<<<(EDG + 255) / 256, 256, 0, stream>>>(src, dst, cur, esrc, EDG);

    // ---- h0 = 0.9*bias, then embedding GEMMs (atomic, split-K; BK=256) ----
    k_binit<<<(NTOT * 128 + 255) / 256, 256, 0, stream>>>(h0, bd, bg);
    gemm_st<2, true, 8><<<dim3(79, 5), 256, 0, stream>>>(
        d_features, 383, 383, 2,
        miT, 2048, 2048, 8, Bdis, 80, h0, NDIS, nullptr);
    gemm_st<1, true, 8><<<dim3(313, 4), 256, 0, stream>>>(
        g_features, 4395, 4395, 18,
        gene_dis, 5000, 5000, 20, Bgen, 304,
        h0 + (size_t)NDIS * 128, NGEN, nullptr);

    // ---- SAGE layer 1: PQ = h0 @ [Ws1|Wn1] (+b1 on P cols), aggregate ----
    gemm_st<0, false, 4><<<dim3(391, 1), 256, 0, stream>>>(
        h0, 128, 128, 1, nullptr, 0, 0, 0, Bs1, 4, PQ, NTOT, b1);
    k_agg<<<NTOT, 64, 0, stream>>>(PQ, rs, esrc, h1, 128, 1);

    // ---- SAGE layer 2 ----
    gemm_st<0, false, 4><<<dim3(391, 1), 256, 0, stream>>>(
        h1, 128, 128, 1, nullptr, 0, 0, 0, Bs2, 4, PQ, NTOT, b2);
    k_agg<<<NTOT, 64, 0, stream>>>(PQ, rs, esrc, (float*)d_out, 64, 0);
}